// Round 5
// baseline (389.637 us; speedup 1.0000x reference)
//
#include <hip/hip_runtime.h>
#include <math.h>

// Problem constants: B=16384, DMODEL=64, NPTS=1323
#define BATCH   16384
#define DMODEL  64
#define NPTS    1323u
#define TOTAL_PTS (16384u * 1323u)            // 21,676,032
#define NBLOCKS   (TOTAL_PTS / 1024u)         // 21,168 blocks x 1024 pts

// 1.5 * log(2*pi)
#define C_15LOG2PI 2.7568155996140194f

typedef float f4 __attribute__((ext_vector_type(4)));

__device__ __forceinline__ float wave_reduce_sum64(float v) {
#pragma unroll
    for (int off = 32; off > 0; off >>= 1)
        v += __shfl_xor(v, off, 64);
    return v;
}

__device__ __forceinline__ float softplus_f(float x) {
    return log1pf(expf(x));   // x in (0,1): no overflow
}
__device__ __forceinline__ float sigmoid_f(float x) {
    return 1.0f / (1.0f + expf(-x));
}

__device__ __forceinline__ float eval_pt(float x, float y, float z,
                                         const f4 q0, const f4 q1, const f4 q2)
{
    const float e0 = x - q0.x;
    const float e1 = y - q0.y;
    const float e2 = z - q0.z;
    const float z0 = e0 * q0.w;
    const float z1 = fmaf(-q1.x, z0, e1) * q1.y;
    const float z2 = fmaf(-q1.w, z1, fmaf(-q1.z, z0, e2)) * q2.x;
    const float maha = fmaf(z0, z0, fmaf(z1, z1, z2 * z2));
    return __expf(fmaf(-0.5f, maha, q2.y));
}

// ---------------------------------------------------------------------------
// R4 kernel (best: 386.4 us) with ONE change: the single coalesced dwordx4
// output store is nontemporal (evict-first). The 87 MB write stream is
// write-once/never-read; nt lets L2 write lines back early+smoothly instead
// of bursty dirty evictions interleaving with the 260 MB read stream.
// Loads stay cached (R1 proved nt loads regress). Everything else identical.
// ---------------------------------------------------------------------------
__global__ __launch_bounds__(256) void mvn_fused_c3nt_kernel(
    const float* __restrict__ rep,    // (B, 64)
    const float* __restrict__ dxyz,   // (B, NPTS, 3)
    const float* __restrict__ Wm,     // (3, 64)
    const float* __restrict__ bm,     // (3,)
    const float* __restrict__ Ws,     // (6, 64)
    const float* __restrict__ bs,     // (6,)
    float* __restrict__ out)          // (B, NPTS)
{
    // params for rows r0, r0+1: (m0,m1,m2,iL00)(L10,iL11,L20,L21)(iL22,cc,0,0)
    __shared__ __attribute__((aligned(16))) float P[2][12];
    // output transpose scratch, one 1KB region per wave (wave-private use)
    __shared__ __attribute__((aligned(16))) float X[4][256];

    const unsigned tid  = threadIdx.x;
    const unsigned wave = tid >> 6;
    const unsigned lane = tid & 63u;
    const unsigned blockPt = blockIdx.x * 1024u;

    // ---- issue the 4 contiguous dwordx3 streaming loads first ----
    const unsigned pbase = blockPt + wave * 256u + lane;
    const float* sp = dxyz + (size_t)pbase * 3u;
    const float x0a = sp[0],   x0b = sp[1],   x0c = sp[2];     // k=0
    const float x1a = sp[192], x1b = sp[193], x1c = sp[194];   // k=1 (+64 pts)
    const float x2a = sp[384], x2b = sp[385], x2c = sp[386];   // k=2
    const float x3a = sp[576], x3b = sp[577], x3c = sp[578];   // k=3

    const unsigned r0 = blockPt / NPTS;            // compiler magic-div
    const unsigned boundary = (r0 + 1u) * NPTS;    // first point of row r0+1

    // ---- param phase (R0-proven): waves 0/1 compute rows r0 / r0+1 ----
    if (wave < 2) {
        const unsigned prow = (wave == 0u) ? r0 : min(r0 + 1u, (unsigned)(BATCH - 1));
        const float r = rep[(size_t)prow * DMODEL + lane];

        float d0 = r * Wm[0*64 + lane];
        float d1 = r * Wm[1*64 + lane];
        float d2 = r * Wm[2*64 + lane];
        float s0 = r * Ws[0*64 + lane];
        float s1 = r * Ws[1*64 + lane];
        float s2 = r * Ws[2*64 + lane];
        float s3 = r * Ws[3*64 + lane];
        float s4 = r * Ws[4*64 + lane];
        float s5 = r * Ws[5*64 + lane];

        d0 = wave_reduce_sum64(d0);
        d1 = wave_reduce_sum64(d1);
        d2 = wave_reduce_sum64(d2);
        s0 = wave_reduce_sum64(s0);
        s1 = wave_reduce_sum64(s1);
        s2 = wave_reduce_sum64(s2);
        s3 = wave_reduce_sum64(s3);
        s4 = wave_reduce_sum64(s4);
        s5 = wave_reduce_sum64(s5);

        if (lane == 0) {
            const float m0 = d0 + bm[0];
            const float m1 = d1 + bm[1];
            const float m2 = d2 + bm[2];

            const float L00 = softplus_f(sigmoid_f(s0 + bs[0]));
            const float L10 = sigmoid_f(s1 + bs[1]);
            const float L11 = softplus_f(sigmoid_f(s2 + bs[2]));
            const float L20 = sigmoid_f(s3 + bs[3]);
            const float L21 = sigmoid_f(s4 + bs[4]);
            const float L22 = softplus_f(sigmoid_f(s5 + bs[5]));

            const float cc = -(logf(L00) + logf(L11) + logf(L22)) - C_15LOG2PI;

            float* Pw = P[wave];
            Pw[0] = m0;         Pw[1] = m1;   Pw[2] = m2;   Pw[3] = 1.0f / L00;
            Pw[4] = L10;        Pw[5] = 1.0f / L11;
            Pw[6] = L20;        Pw[7] = L21;
            Pw[8] = 1.0f / L22; Pw[9] = cc;   Pw[10] = 0.0f; Pw[11] = 0.0f;
        }
    }
    __syncthreads();

    // both rows' params into registers (broadcast LDS reads)
    const f4* Pa = (const f4*)P[0];
    const f4 A0 = Pa[0], A1 = Pa[1], A2 = Pa[2];
    const f4* Pb = (const f4*)P[1];
    const f4 B0 = Pb[0], B1 = Pb[1], B2 = Pb[2];

    // ---- evaluate 4 points; row selection = one compare per point ----
    float r0v, r1v, r2v, r3v;
    if (pbase + 192u < boundary) {
        // all 4 points in row r0 (vast majority of threads)
        r0v = eval_pt(x0a, x0b, x0c, A0, A1, A2);
        r1v = eval_pt(x1a, x1b, x1c, A0, A1, A2);
        r2v = eval_pt(x2a, x2b, x2c, A0, A1, A2);
        r3v = eval_pt(x3a, x3b, x3c, A0, A1, A2);
    } else if (pbase >= boundary) {
        // all 4 points in row r0+1
        r0v = eval_pt(x0a, x0b, x0c, B0, B1, B2);
        r1v = eval_pt(x1a, x1b, x1c, B0, B1, B2);
        r2v = eval_pt(x2a, x2b, x2c, B0, B1, B2);
        r3v = eval_pt(x3a, x3b, x3c, B0, B1, B2);
    } else {
        // straddling thread: per-point select
#define EVP(K, XA, XB, XC, DST)                                           \
        {                                                                 \
            const bool in0 = (pbase + (K) * 64u) < boundary;              \
            const f4 q0 = in0 ? A0 : B0;                                  \
            const f4 q1 = in0 ? A1 : B1;                                  \
            const f4 q2 = in0 ? A2 : B2;                                  \
            DST = eval_pt(XA, XB, XC, q0, q1, q2);                        \
        }
        EVP(0u, x0a, x0b, x0c, r0v)
        EVP(1u, x1a, x1b, x1c, r1v)
        EVP(2u, x2a, x2b, x2c, r2v)
        EVP(3u, x3a, x3b, x3c, r3v)
#undef EVP
    }

    // ---- wave-private LDS transpose -> one coalesced dwordx4 nt store ----
    float* Xw = X[wave];
    Xw[lane]        = r0v;    // lane-stride 4B: conflict-free
    Xw[lane + 64u]  = r1v;
    Xw[lane + 128u] = r2v;
    Xw[lane + 192u] = r3v;
    // same-wave RAW on LDS: hardware-ordered via lgkmcnt (compiler inserts)
    const f4 o = ((const f4*)Xw)[lane];   // contiguous b128, conflict-free
    __builtin_nontemporal_store(o, (f4*)out + blockIdx.x * 256u + wave * 64u + lane);
}

extern "C" void kernel_launch(void* const* d_in, const int* in_sizes, int n_in,
                              void* d_out, int out_size, void* d_ws, size_t ws_size,
                              hipStream_t stream) {
    const float* rep  = (const float*)d_in[0];
    const float* dxyz = (const float*)d_in[1];
    const float* Wm   = (const float*)d_in[2];
    const float* bm   = (const float*)d_in[3];
    const float* Ws   = (const float*)d_in[4];
    const float* bs   = (const float*)d_in[5];
    float* out = (float*)d_out;

    mvn_fused_c3nt_kernel<<<NBLOCKS, 256, 0, stream>>>(rep, dxyz, Wm, bm, Ws, bs, out);
}

// Round 6
// 386.712 us; speedup vs baseline: 1.0076x; 1.0076x over previous
//
#include <hip/hip_runtime.h>
#include <math.h>

// Problem constants: B=16384, DMODEL=64, NPTS=1323
#define BATCH   16384
#define DMODEL  64
#define NPTS    1323u
#define TOTAL_PTS (16384u * 1323u)            // 21,676,032
#define NBLOCKS   (TOTAL_PTS / 1024u)         // 21,168 blocks x 1024 pts

// 1.5 * log(2*pi)
#define C_15LOG2PI 2.7568155996140194f

typedef float f4 __attribute__((ext_vector_type(4)));

__device__ __forceinline__ float wave_reduce_sum64(float v) {
#pragma unroll
    for (int off = 32; off > 0; off >>= 1)
        v += __shfl_xor(v, off, 64);
    return v;
}

__device__ __forceinline__ float softplus_f(float x) {
    return log1pf(expf(x));   // x in (0,1): no overflow
}
__device__ __forceinline__ float sigmoid_f(float x) {
    return 1.0f / (1.0f + expf(-x));
}

__device__ __forceinline__ float eval_pt(float x, float y, float z,
                                         const f4 q0, const f4 q1, const f4 q2)
{
    const float e0 = x - q0.x;
    const float e1 = y - q0.y;
    const float e2 = z - q0.z;
    const float z0 = e0 * q0.w;
    const float z1 = fmaf(-q1.x, z0, e1) * q1.y;
    const float z2 = fmaf(-q1.w, z1, fmaf(-q1.z, z0, e2)) * q2.x;
    const float maha = fmaf(z0, z0, fmaf(z1, z1, z2 * z2));
    return __expf(fmaf(-0.5f, maha, q2.y));
}

// ---------------------------------------------------------------------------
// FINAL (revert to R4, session best: 386.4 us).
// 21168 blocks x 1024 pts; in-block param phase hidden under streaming loads;
// contiguous 12B/lane dwordx3 loads (each instruction covers a dense 768B
// segment); wave-private LDS transpose -> one coalesced dwordx4 store.
// Cached (non-nt) loads AND stores: nt regressed in both R1 and R5.
// ---------------------------------------------------------------------------
__global__ __launch_bounds__(256) void mvn_fused_c3_kernel(
    const float* __restrict__ rep,    // (B, 64)
    const float* __restrict__ dxyz,   // (B, NPTS, 3)
    const float* __restrict__ Wm,     // (3, 64)
    const float* __restrict__ bm,     // (3,)
    const float* __restrict__ Ws,     // (6, 64)
    const float* __restrict__ bs,     // (6,)
    float* __restrict__ out)          // (B, NPTS)
{
    // params for rows r0, r0+1: (m0,m1,m2,iL00)(L10,iL11,L20,L21)(iL22,cc,0,0)
    __shared__ __attribute__((aligned(16))) float P[2][12];
    // output transpose scratch, one 1KB region per wave (wave-private use)
    __shared__ __attribute__((aligned(16))) float X[4][256];

    const unsigned tid  = threadIdx.x;
    const unsigned wave = tid >> 6;
    const unsigned lane = tid & 63u;
    const unsigned blockPt = blockIdx.x * 1024u;

    // ---- issue the 4 contiguous dwordx3 streaming loads first ----
    const unsigned pbase = blockPt + wave * 256u + lane;
    const float* sp = dxyz + (size_t)pbase * 3u;
    const float x0a = sp[0],   x0b = sp[1],   x0c = sp[2];     // k=0
    const float x1a = sp[192], x1b = sp[193], x1c = sp[194];   // k=1 (+64 pts)
    const float x2a = sp[384], x2b = sp[385], x2c = sp[386];   // k=2
    const float x3a = sp[576], x3b = sp[577], x3c = sp[578];   // k=3

    const unsigned r0 = blockPt / NPTS;            // compiler magic-div
    const unsigned boundary = (r0 + 1u) * NPTS;    // first point of row r0+1

    // ---- param phase: waves 0/1 compute rows r0 / r0+1 (hidden under loads) ----
    if (wave < 2) {
        const unsigned prow = (wave == 0u) ? r0 : min(r0 + 1u, (unsigned)(BATCH - 1));
        const float r = rep[(size_t)prow * DMODEL + lane];

        float d0 = r * Wm[0*64 + lane];
        float d1 = r * Wm[1*64 + lane];
        float d2 = r * Wm[2*64 + lane];
        float s0 = r * Ws[0*64 + lane];
        float s1 = r * Ws[1*64 + lane];
        float s2 = r * Ws[2*64 + lane];
        float s3 = r * Ws[3*64 + lane];
        float s4 = r * Ws[4*64 + lane];
        float s5 = r * Ws[5*64 + lane];

        d0 = wave_reduce_sum64(d0);
        d1 = wave_reduce_sum64(d1);
        d2 = wave_reduce_sum64(d2);
        s0 = wave_reduce_sum64(s0);
        s1 = wave_reduce_sum64(s1);
        s2 = wave_reduce_sum64(s2);
        s3 = wave_reduce_sum64(s3);
        s4 = wave_reduce_sum64(s4);
        s5 = wave_reduce_sum64(s5);

        if (lane == 0) {
            const float m0 = d0 + bm[0];
            const float m1 = d1 + bm[1];
            const float m2 = d2 + bm[2];

            const float L00 = softplus_f(sigmoid_f(s0 + bs[0]));
            const float L10 = sigmoid_f(s1 + bs[1]);
            const float L11 = softplus_f(sigmoid_f(s2 + bs[2]));
            const float L20 = sigmoid_f(s3 + bs[3]);
            const float L21 = sigmoid_f(s4 + bs[4]);
            const float L22 = softplus_f(sigmoid_f(s5 + bs[5]));

            const float cc = -(logf(L00) + logf(L11) + logf(L22)) - C_15LOG2PI;

            float* Pw = P[wave];
            Pw[0] = m0;         Pw[1] = m1;   Pw[2] = m2;   Pw[3] = 1.0f / L00;
            Pw[4] = L10;        Pw[5] = 1.0f / L11;
            Pw[6] = L20;        Pw[7] = L21;
            Pw[8] = 1.0f / L22; Pw[9] = cc;   Pw[10] = 0.0f; Pw[11] = 0.0f;
        }
    }
    __syncthreads();

    // both rows' params into registers (broadcast LDS reads)
    const f4* Pa = (const f4*)P[0];
    const f4 A0 = Pa[0], A1 = Pa[1], A2 = Pa[2];
    const f4* Pb = (const f4*)P[1];
    const f4 B0 = Pb[0], B1 = Pb[1], B2 = Pb[2];

    // ---- evaluate 4 points; row selection = one compare per point ----
    float r0v, r1v, r2v, r3v;
    if (pbase + 192u < boundary) {
        // all 4 points in row r0 (vast majority of threads)
        r0v = eval_pt(x0a, x0b, x0c, A0, A1, A2);
        r1v = eval_pt(x1a, x1b, x1c, A0, A1, A2);
        r2v = eval_pt(x2a, x2b, x2c, A0, A1, A2);
        r3v = eval_pt(x3a, x3b, x3c, A0, A1, A2);
    } else if (pbase >= boundary) {
        // all 4 points in row r0+1
        r0v = eval_pt(x0a, x0b, x0c, B0, B1, B2);
        r1v = eval_pt(x1a, x1b, x1c, B0, B1, B2);
        r2v = eval_pt(x2a, x2b, x2c, B0, B1, B2);
        r3v = eval_pt(x3a, x3b, x3c, B0, B1, B2);
    } else {
        // straddling thread: per-point select
#define EVP(K, XA, XB, XC, DST)                                           \
        {                                                                 \
            const bool in0 = (pbase + (K) * 64u) < boundary;              \
            const f4 q0 = in0 ? A0 : B0;                                  \
            const f4 q1 = in0 ? A1 : B1;                                  \
            const f4 q2 = in0 ? A2 : B2;                                  \
            DST = eval_pt(XA, XB, XC, q0, q1, q2);                        \
        }
        EVP(0u, x0a, x0b, x0c, r0v)
        EVP(1u, x1a, x1b, x1c, r1v)
        EVP(2u, x2a, x2b, x2c, r2v)
        EVP(3u, x3a, x3b, x3c, r3v)
#undef EVP
    }

    // ---- wave-private LDS transpose -> one coalesced dwordx4 store ----
    float* Xw = X[wave];
    Xw[lane]        = r0v;    // lane-stride 4B: conflict-free
    Xw[lane + 64u]  = r1v;
    Xw[lane + 128u] = r2v;
    Xw[lane + 192u] = r3v;
    // same-wave RAW on LDS: hardware-ordered via lgkmcnt (compiler inserts)
    const f4 o = ((const f4*)Xw)[lane];   // contiguous b128, conflict-free
    ((f4*)out)[blockIdx.x * 256u + wave * 64u + lane] = o;
}

extern "C" void kernel_launch(void* const* d_in, const int* in_sizes, int n_in,
                              void* d_out, int out_size, void* d_ws, size_t ws_size,
                              hipStream_t stream) {
    const float* rep  = (const float*)d_in[0];
    const float* dxyz = (const float*)d_in[1];
    const float* Wm   = (const float*)d_in[2];
    const float* bm   = (const float*)d_in[3];
    const float* Ws   = (const float*)d_in[4];
    const float* bs   = (const float*)d_in[5];
    float* out = (float*)d_out;

    mvn_fused_c3_kernel<<<NBLOCKS, 256, 0, stream>>>(rep, dxyz, Wm, bm, Ws, bs, out);
}